// Round 1
// baseline (213.374 us; speedup 1.0000x reference)
//
#include <hip/hip_runtime.h>

// Bilateral slice: grid (N=4, C=12, GD=8, GH=16, GW=16) fp32,
// guide (N,1,1024,1024) fp32 -> out (N, C, 1024, 1024) fp32.
//
// Strategy: one block per image row. y-lerp of the grid is wave-uniform per
// row -> precompute r[c][z][gx] in LDS once per block (1536 floats), then each
// pixel does a 4-tap (x,z) bilinear per channel instead of 8-tap trilinear.
// Edge clamping folded into adjusted t (base clamped to [0, dim-2], t shifted
// into [0,1]) — algebraically identical to clip-index-keep-weight.

#define NN 4
#define CC 12
#define GD_ 8
#define GH_ 16
#define GW_ 16
#define HH 1024
#define WW 1024

// LDS: r[c][z][gx], z-stride 17 (bank spread for random z), c-stride 136.
#define ZSTR 17
#define CSTR (GD_ * ZSTR)  // 136

__global__ __launch_bounds__(256) void slice_kernel(
    const float* __restrict__ grid,   // (N, C, GD, GH, GW)
    const float* __restrict__ guide,  // (N, 1, H, W)
    float* __restrict__ out)          // (N, C, H, W)
{
    __shared__ float r[CC * CSTR + 8];

    const int row = blockIdx.x;        // 0 .. N*H-1
    const int n   = row >> 10;
    const int y   = row & (HH - 1);
    const int tid = threadIdx.x;

    // ---- y weights (wave-uniform across the row) ----
    float ys = ((float)y + 0.5f) * (1.0f / 64.0f);   // * GH / H
    float fy = floorf(ys - 0.5f);
    int   by = (int)fy;
    by = by < 0 ? 0 : (by > GH_ - 2 ? GH_ - 2 : by);
    float ty = (ys - 0.5f - fy) + (float)((int)fy - by);
    ty = ty < 0.0f ? 0.0f : (ty > 1.0f ? 1.0f : ty);
    const float wy0 = 1.0f - ty, wy1 = ty;

    // ---- stage y-lerped grid rows into LDS ----
    const float* gbase = grid + (size_t)n * (CC * GD_ * GH_ * GW_);
    for (int idx = tid; idx < CC * GD_ * GW_; idx += 256) {
        int gx = idx & 15;
        int z  = (idx >> 4) & 7;
        int c  = idx >> 7;
        const float* gp = gbase + ((c * GD_ + z) * GH_) * GW_ + gx;
        float g0 = gp[by * GW_];
        float g1 = gp[(by + 1) * GW_];
        r[c * CSTR + z * ZSTR + gx] = wy0 * g0 + wy1 * g1;
    }
    __syncthreads();

    // ---- per-pixel setup: 4 consecutive pixels per thread ----
    const float4 g4 = ((const float4*)guide)[((size_t)n * HH + y) * (WW / 4) + tid];
    float gz[4] = {g4.x, g4.y, g4.z, g4.w};

    int   off0[4];
    float w00[4], w01[4], w10[4], w11[4];
#pragma unroll
    for (int j = 0; j < 4; ++j) {
        int   x  = tid * 4 + j;
        float xs = ((float)x + 0.5f) * (1.0f / 64.0f);  // * GW / W
        float fx = floorf(xs - 0.5f);
        int   bx = (int)fx;
        bx = bx < 0 ? 0 : (bx > GW_ - 2 ? GW_ - 2 : bx);
        float tx = (xs - 0.5f - fx) + (float)((int)fx - bx);
        tx = tx < 0.0f ? 0.0f : (tx > 1.0f ? 1.0f : tx);

        float zs = gz[j] * 8.0f;                        // * GD
        float fz = floorf(zs - 0.5f);
        int   bz = (int)fz;
        bz = bz < 0 ? 0 : (bz > GD_ - 2 ? GD_ - 2 : bz);
        float tz = (zs - 0.5f - fz) + (float)((int)fz - bz);
        tz = tz < 0.0f ? 0.0f : (tz > 1.0f ? 1.0f : tz);

        off0[j] = bz * ZSTR + bx;
        float tx0 = 1.0f - tx, tz0 = 1.0f - tz;
        w00[j] = tz0 * tx0;  w01[j] = tz0 * tx;
        w10[j] = tz  * tx0;  w11[j] = tz  * tx;
    }

    // ---- channel loop: 4-tap bilinear from LDS, float4 store ----
    float4* out4 = (float4*)out;
#pragma unroll
    for (int c = 0; c < CC; ++c) {
        const float* rc = r + c * CSTR;
        float acc[4];
#pragma unroll
        for (int j = 0; j < 4; ++j) {
            const float* p0 = rc + off0[j];
            float a0 = p0[0],    a1 = p0[1];
            float b0 = p0[ZSTR], b1 = p0[ZSTR + 1];
            acc[j] = w00[j] * a0 + w01[j] * a1 + w10[j] * b0 + w11[j] * b1;
        }
        out4[(((size_t)n * CC + c) * HH + y) * (WW / 4) + tid] =
            make_float4(acc[0], acc[1], acc[2], acc[3]);
    }
}

extern "C" void kernel_launch(void* const* d_in, const int* in_sizes, int n_in,
                              void* d_out, int out_size, void* d_ws, size_t ws_size,
                              hipStream_t stream) {
    const float* grid  = (const float*)d_in[0];
    const float* guide = (const float*)d_in[1];
    float* out = (float*)d_out;
    dim3 gridDim(NN * HH);
    dim3 blockDim(256);
    hipLaunchKernelGGL(slice_kernel, gridDim, blockDim, 0, stream, grid, guide, out);
}